// Round 16
// baseline (123.498 us; speedup 1.0000x reference)
//
#include <hip/hip_runtime.h>
#include <hip/hip_bf16.h>

#define NRES 256
#define CH   128
#define NH   4
#define HD   32
#define NPX  (NRES*NRES)   // 65536 pixels
#define BPX  64            // pixels per block in GEMM kernels
#define LOG2E 1.4426950408889634f

typedef __hip_bfloat16 bf16;
typedef __attribute__((ext_vector_type(8))) short bf16x8;
typedef __attribute__((ext_vector_type(4))) float f32x4;
typedef __attribute__((ext_vector_type(16))) float f32x16;
typedef __attribute__((ext_vector_type(2))) unsigned int uint2v;

__device__ __forceinline__ float lo_f(unsigned u) { return __uint_as_float(u << 16); }
__device__ __forceinline__ float hi_f(unsigned u) { return __uint_as_float(u & 0xffff0000u); }
__device__ __forceinline__ float fexp2(float x) { return __builtin_amdgcn_exp2f(x); }
__device__ __forceinline__ unsigned pk2(float a, float b) {
    unsigned short ua = __bfloat16_as_ushort(__float2bfloat16(a));
    unsigned short ub = __bfloat16_as_ushort(__float2bfloat16(b));
    return (unsigned)ua | ((unsigned)ub << 16);
}

// ---------------- Kernel 0: convert weights f32 -> bf16 ----------------
__global__ __launch_bounds__(256) void prep_kernel(const float* __restrict__ wq,
                                                   const float* __restrict__ wk,
                                                   const float* __restrict__ wv,
                                                   const float* __restrict__ wg,
                                                   const float* __restrict__ wo,
                                                   bf16* __restrict__ dst) {
    int mat = blockIdx.x >> 4;
    int off = ((blockIdx.x & 15) * 256 + threadIdx.x) * 4;
    const float* srcs[5] = {wq, wk, wv, wg, wo};
    float4 v4 = *reinterpret_cast<const float4*>(srcs[mat] + off);
    uint2 o;
    o.x = pk2(v4.x, v4.y);
    o.y = pk2(v4.z, v4.w);
    *reinterpret_cast<uint2*>(dst + (size_t)mat * 16384 + off) = o;
}

// ---------------- Kernel 1: LN (in registers) + MFMA projections + pair bias ----------------
__global__ __launch_bounds__(256) void proj_kernel(const float* __restrict__ x2d,
                                                   const float* __restrict__ nw,
                                                   const float* __restrict__ nb,
                                                   const bf16* __restrict__ wgt,
                                                   const float* __restrict__ bg,
                                                   const float* __restrict__ wb,
                                                   bf16* __restrict__ q,
                                                   bf16* __restrict__ k,
                                                   bf16* __restrict__ v,
                                                   bf16* __restrict__ g,
                                                   float* __restrict__ bias) {
    __shared__ short xsb[BPX][128];    // 16 KB swizzled bf16 tile
    int t = threadIdx.x;
    size_t pbase = (size_t)blockIdx.x * BPX;
    int px = t >> 2, lo = t & 3;

    const float* xrow = x2d + (pbase + px) * CH;
    float4 v4[8];
    #pragma unroll
    for (int cc = 0; cc < 8; ++cc)
        v4[cc] = *reinterpret_cast<const float4*>(xrow + 16 * cc + 4 * lo);

    float s = 0.f, ss = 0.f;
    #pragma unroll
    for (int cc = 0; cc < 8; ++cc) {
        s  += v4[cc].x + v4[cc].y + v4[cc].z + v4[cc].w;
        ss += v4[cc].x * v4[cc].x + v4[cc].y * v4[cc].y
            + v4[cc].z * v4[cc].z + v4[cc].w * v4[cc].w;
    }
    s += __shfl_xor(s, 1); ss += __shfl_xor(ss, 1);
    s += __shfl_xor(s, 2); ss += __shfl_xor(ss, 2);
    float mu  = s * (1.0f / CH);
    float var = ss * (1.0f / CH) - mu * mu;
    float rs  = rsqrtf(var + 1e-5f);

    #pragma unroll
    for (int cc = 0; cc < 8; ++cc) {
        int c0 = 16 * cc + 4 * lo;
        float4 wv = *reinterpret_cast<const float4*>(nw + c0);
        float4 bv = *reinterpret_cast<const float4*>(nb + c0);
        v4[cc].x = (v4[cc].x - mu) * rs * wv.x + bv.x;
        v4[cc].y = (v4[cc].y - mu) * rs * wv.y + bv.y;
        v4[cc].z = (v4[cc].z - mu) * rs * wv.z + bv.z;
        v4[cc].w = (v4[cc].w - mu) * rs * wv.w + bv.w;
        int sc = ((((c0 >> 3) ^ px) & 7) << 3) | (c0 & 7) | (c0 & 64);
        uint2 pw;
        pw.x = pk2(v4[cc].x, v4[cc].y);
        pw.y = pk2(v4[cc].z, v4[cc].w);
        *reinterpret_cast<uint2*>(&xsb[px][sc]) = pw;
    }

    // pair bias partials; bias layout [h][i][j] == [h][p], coalesced writes
    float bp0 = 0.f, bp1 = 0.f, bp2 = 0.f, bp3 = 0.f;
    #pragma unroll
    for (int cc = 0; cc < 8; ++cc) {
        int c0 = 16 * cc + 4 * lo;
        float4 w0 = *reinterpret_cast<const float4*>(wb + 0 * CH + c0);
        float4 w1 = *reinterpret_cast<const float4*>(wb + 1 * CH + c0);
        float4 w2 = *reinterpret_cast<const float4*>(wb + 2 * CH + c0);
        float4 w3 = *reinterpret_cast<const float4*>(wb + 3 * CH + c0);
        bp0 += v4[cc].x * w0.x + v4[cc].y * w0.y + v4[cc].z * w0.z + v4[cc].w * w0.w;
        bp1 += v4[cc].x * w1.x + v4[cc].y * w1.y + v4[cc].z * w1.z + v4[cc].w * w1.w;
        bp2 += v4[cc].x * w2.x + v4[cc].y * w2.y + v4[cc].z * w2.z + v4[cc].w * w2.w;
        bp3 += v4[cc].x * w3.x + v4[cc].y * w3.y + v4[cc].z * w3.z + v4[cc].w * w3.w;
    }
    bp0 += __shfl_xor(bp0, 1); bp0 += __shfl_xor(bp0, 2);
    bp1 += __shfl_xor(bp1, 1); bp1 += __shfl_xor(bp1, 2);
    bp2 += __shfl_xor(bp2, 1); bp2 += __shfl_xor(bp2, 2);
    bp3 += __shfl_xor(bp3, 1); bp3 += __shfl_xor(bp3, 2);
    {
        float bv = (lo == 0) ? bp0 : (lo == 1) ? bp1 : (lo == 2) ? bp2 : bp3;
        bias[(size_t)lo * NPX + pbase + px] = bv * LOG2E;
    }
    __syncthreads();

    int w  = t >> 6, l = t & 63;
    int ll = l & 15, lg = l >> 4;
    bf16* Os[4] = {q, k, v, g};
    const float qscale = 0.17677669529663689f * LOG2E;   // 1/sqrt(32) * log2(e)

    #pragma unroll
    for (int mat = 0; mat < 4; ++mat) {
        const bf16* W = wgt + (size_t)mat * 16384;
        bf16x8 bfr[2][4];
        #pragma unroll
        for (int p = 0; p < 2; ++p)
            #pragma unroll
            for (int kt = 0; kt < 4; ++kt)
                bfr[p][kt] = *reinterpret_cast<const bf16x8*>(
                    W + (size_t)((2 * w + p) * 16 + ll) * CH + kt * 32 + lg * 8);

        f32x4 acc[4][2];
        #pragma unroll
        for (int mt = 0; mt < 4; ++mt)
            #pragma unroll
            for (int p = 0; p < 2; ++p) acc[mt][p] = (f32x4){0.f, 0.f, 0.f, 0.f};

        #pragma unroll
        for (int kt = 0; kt < 4; ++kt) {
            bf16x8 a[4];
            #pragma unroll
            for (int mt = 0; mt < 4; ++mt) {
                int row = 16 * mt + ll;
                int gr  = (kt * 4 + lg) ^ (row & 7);
                a[mt] = *reinterpret_cast<const bf16x8*>(&xsb[row][gr * 8]);
            }
            #pragma unroll
            for (int mt = 0; mt < 4; ++mt)
                #pragma unroll
                for (int p = 0; p < 2; ++p)
                    acc[mt][p] = __builtin_amdgcn_mfma_f32_16x16x32_bf16(a[mt], bfr[p][kt], acc[mt][p], 0, 0, 0);
        }

        #pragma unroll
        for (int p = 0; p < 2; ++p) {
            int o = (2 * w + p) * 16 + ll;
            float bgv = (mat == 3) ? bg[o] : 0.f;
            #pragma unroll
            for (int mt = 0; mt < 4; ++mt) {
                #pragma unroll
                for (int r = 0; r < 4; ++r) {
                    int prow = 16 * mt + lg * 4 + r;
                    float valf = acc[mt][p][r];
                    if (mat == 0) valf *= qscale;
                    if (mat == 3) valf = 1.f / (1.f + __expf(-(valf + bgv)));
                    Os[mat][(pbase + prow) * CH + o] = __float2bfloat16(valf);
                }
            }
        }
    }
}

// ---------------- Kernel 2: MFMA flash attention per (m,h), 8 waves x 32 q-rows ----------------
// 512 threads: full-machine occupancy at 4 blocks/CU; V staged once; R12-verified wave body
__global__ __launch_bounds__(512, 8) void attn_kernel(const bf16* q,
                                                      const bf16* __restrict__ kk,
                                                      const bf16* __restrict__ vv,
                                                      const float* __restrict__ bias,
                                                      const bf16* __restrict__ gg,
                                                      bf16* attn) {
    __shared__ short vt[HD][NRES];     // 16 KB, transposed V, granule-XOR swizzled

    int t   = threadIdx.x;
    int w   = t >> 6;        // 0..7
    int l   = t & 63;
    int l31 = l & 31;
    int hi5 = l >> 5;
    int m = blockIdx.x, h = blockIdx.y;
    size_t base = ((size_t)m * NRES) * CH + (size_t)h * HD;
    int ibase = w * 32;

    // stage V transposed + swizzled (512 threads, 2 iters)
    for (int it = 0; it < 2; ++it) {
        int e8 = t + 512 * it;          // 0..1023
        int j  = e8 >> 2;
        int d0 = (e8 & 3) * 8;
        uint4 vu = *reinterpret_cast<const uint4*>(vv + base + (size_t)j * CH + d0);
        union { uint4 u; short s[8]; } vc; vc.u = vu;
        #pragma unroll
        for (int s = 0; s < 8; ++s)
            vt[d0 + s][j ^ (8 * s)] = vc.s[s];
    }

    // Q fragments (B-operand): col i = ibase + l31, k = 16*tt + 8*hi5 + e
    bf16x8 qf0 = *reinterpret_cast<const bf16x8*>(q + base + (size_t)(ibase + l31) * CH + hi5 * 8);
    bf16x8 qf1 = *reinterpret_cast<const bf16x8*>(q + base + (size_t)(ibase + l31) * CH + 16 + hi5 * 8);

    __syncthreads();

    float m_run = -1e30f, l_run = 0.f;
    f32x16 oacc;
    #pragma unroll
    for (int r = 0; r < 16; ++r) oacc[r] = 0.f;

    const float* bh = bias + (size_t)h * NPX;

    for (int jt = 0; jt < 8; ++jt) {
        int j0 = jt * 32;

        // K fragments (A-operand): row j = j0 + l31, k = d
        bf16x8 kf0 = *reinterpret_cast<const bf16x8*>(kk + base + (size_t)(j0 + l31) * CH + hi5 * 8);
        bf16x8 kf1 = *reinterpret_cast<const bf16x8*>(kk + base + (size_t)(j0 + l31) * CH + 16 + hi5 * 8);

        // S^T tile: C col i = l31, row j_local = (r&3)+8*(r>>2)+4*hi5
        f32x16 sac;
        #pragma unroll
        for (int r = 0; r < 16; ++r) sac[r] = 0.f;
        sac = __builtin_amdgcn_mfma_f32_32x32x16_bf16(kf0, qf0, sac, 0, 0, 0);
        sac = __builtin_amdgcn_mfma_f32_32x32x16_bf16(kf1, qf1, sac, 0, 0, 0);

        // bias add (exp2 domain): float4 over r-consecutive j
        {
            int i = ibase + l31;
            #pragma unroll
            for (int rq = 0; rq < 4; ++rq) {
                float4 b4 = *reinterpret_cast<const float4*>(bh + (size_t)i * NRES + j0 + 8 * rq + 4 * hi5);
                sac[4 * rq + 0] += b4.x; sac[4 * rq + 1] += b4.y;
                sac[4 * rq + 2] += b4.z; sac[4 * rq + 3] += b4.w;
            }
        }

        // online softmax (exp2 domain), defer-max
        {
            float a0 = fmaxf(sac[0], sac[1]),  a1 = fmaxf(sac[2], sac[3]);
            float a2 = fmaxf(sac[4], sac[5]),  a3 = fmaxf(sac[6], sac[7]);
            float a4 = fmaxf(sac[8], sac[9]),  a5 = fmaxf(sac[10], sac[11]);
            float a6 = fmaxf(sac[12], sac[13]), a7 = fmaxf(sac[14], sac[15]);
            float mx = fmaxf(fmaxf(fmaxf(a0, a1), fmaxf(a2, a3)), fmaxf(fmaxf(a4, a5), fmaxf(a6, a7)));
            mx = fmaxf(mx, __shfl_xor(mx, 32));

            if (!__all(mx <= m_run + 8.f)) {
                float mnew = fmaxf(m_run, mx);
                float sc = fexp2(m_run - mnew);
                l_run *= sc;
                #pragma unroll
                for (int r = 0; r < 16; ++r) oacc[r] *= sc;
                m_run = mnew;
            }
            #pragma unroll
            for (int r = 0; r < 16; ++r) sac[r] = fexp2(sac[r] - m_run);
            float s0 = sac[0] + sac[1],  s1 = sac[2] + sac[3];
            float s2 = sac[4] + sac[5],  s3 = sac[6] + sac[7];
            float s4 = sac[8] + sac[9],  s5 = sac[10] + sac[11];
            float s6 = sac[12] + sac[13], s7 = sac[14] + sac[15];
            float psum = ((s0 + s1) + (s2 + s3)) + ((s4 + s5) + (s6 + s7));
            psum += __shfl_xor(psum, 32);
            l_run += psum;
        }

        // PV: O^T += V^T * P^T; P B-frag via permlane32_swap
        __builtin_amdgcn_s_setprio(1);
        #pragma unroll
        for (int tt = 0; tt < 2; ++tt) {
            bf16x8 vf = *reinterpret_cast<const bf16x8*>(
                &vt[l31][(j0 + 16 * tt + 8 * hi5) ^ (8 * (l31 & 7))]);
            unsigned x0 = pk2(sac[8 * tt + 0], sac[8 * tt + 1]);
            unsigned x1 = pk2(sac[8 * tt + 2], sac[8 * tt + 3]);
            unsigned y0 = pk2(sac[8 * tt + 4], sac[8 * tt + 5]);
            unsigned y1 = pk2(sac[8 * tt + 6], sac[8 * tt + 7]);
            uint2v r0 = __builtin_amdgcn_permlane32_swap(x0, y0, false, false);
            uint2v r1 = __builtin_amdgcn_permlane32_swap(x1, y1, false, false);
            union { unsigned u[4]; bf16x8 v; } pf;
            pf.u[0] = r0[0];  // k 0,1
            pf.u[1] = r1[0];  // k 2,3
            pf.u[2] = r0[1];  // k 4,5
            pf.u[3] = r1[1];  // k 6,7
            oacc = __builtin_amdgcn_mfma_f32_32x32x16_bf16(vf, pf.v, oacc, 0, 0, 0);
        }
        __builtin_amdgcn_s_setprio(0);
    }

    // epilogue: normalize, gate, store; C col i = l31, row d = (r&3)+8*(r>>2)+4*hi5
    {
        float inv = 1.f / l_run;
        size_t prow = base + (size_t)(ibase + l31) * CH;
        #pragma unroll
        for (int rq = 0; rq < 4; ++rq) {
            int d0 = 8 * rq + 4 * hi5;
            uint2 gu = *reinterpret_cast<const uint2*>(gg + prow + d0);
            float g0 = lo_f(gu.x), g1 = hi_f(gu.x), g2 = lo_f(gu.y), g3 = hi_f(gu.y);
            uint2 ow;
            ow.x = pk2(oacc[4 * rq + 0] * inv * g0, oacc[4 * rq + 1] * inv * g1);
            ow.y = pk2(oacc[4 * rq + 2] * inv * g2, oacc[4 * rq + 3] * inv * g3);
            *reinterpret_cast<uint2*>(attn + prow + d0) = ow;
        }
    }
}

// ---------------- Kernel 3: MFMA output projection (f32 out) ----------------
__global__ __launch_bounds__(256) void out_kernel(const bf16* __restrict__ ga,
                                                  const bf16* __restrict__ wob,
                                                  const float* __restrict__ bo,
                                                  float* __restrict__ out) {
    __shared__ short xsb[BPX][128];
    int t = threadIdx.x;
    size_t pbase = (size_t)blockIdx.x * BPX;

    for (int it = 0; it < 4; ++it) {
        int idx = (it * 256 + t) * 8;
        int px = idx >> 7, c = idx & 127;
        int gr = c >> 3;
        uint4 u = *reinterpret_cast<const uint4*>(ga + pbase * CH + idx);
        *reinterpret_cast<uint4*>(&xsb[px][(gr ^ (px & 7)) * 8]) = u;
    }
    __syncthreads();

    int w  = t >> 6, l = t & 63;
    int ll = l & 15, lg = l >> 4;

    bf16x8 bfr[2][4];
    #pragma unroll
    for (int p = 0; p < 2; ++p)
        #pragma unroll
        for (int kt = 0; kt < 4; ++kt)
            bfr[p][kt] = *reinterpret_cast<const bf16x8*>(
                wob + (size_t)((2 * w + p) * 16 + ll) * CH + kt * 32 + lg * 8);

    f32x4 acc[4][2];
    #pragma unroll
    for (int mt = 0; mt < 4; ++mt)
        #pragma unroll
        for (int p = 0; p < 2; ++p) acc[mt][p] = (f32x4){0.f, 0.f, 0.f, 0.f};

    #pragma unroll
    for (int kt = 0; kt < 4; ++kt) {
        bf16x8 a[4];
        #pragma unroll
        for (int mt = 0; mt < 4; ++mt) {
            int row = 16 * mt + ll;
            int gr  = (kt * 4 + lg) ^ (row & 7);
            a[mt] = *reinterpret_cast<const bf16x8*>(&xsb[row][gr * 8]);
        }
        #pragma unroll
        for (int mt = 0; mt < 4; ++mt)
            #pragma unroll
            for (int p = 0; p < 2; ++p)
                acc[mt][p] = __builtin_amdgcn_mfma_f32_16x16x32_bf16(a[mt], bfr[p][kt], acc[mt][p], 0, 0, 0);
    }

    #pragma unroll
    for (int p = 0; p < 2; ++p) {
        int o = (2 * w + p) * 16 + ll;
        float bov = bo[o];
        #pragma unroll
        for (int mt = 0; mt < 4; ++mt)
            #pragma unroll
            for (int r = 0; r < 4; ++r) {
                int prow = 16 * mt + lg * 4 + r;
                out[(pbase + prow) * CH + o] = acc[mt][p][r] + bov;
            }
    }
}

extern "C" void kernel_launch(void* const* d_in, const int* in_sizes, int n_in,
                              void* d_out, int out_size, void* d_ws, size_t ws_size,
                              hipStream_t stream) {
    const float* x2d = (const float*)d_in[0];
    const float* nw  = (const float*)d_in[1];
    const float* nb  = (const float*)d_in[2];
    const float* wq  = (const float*)d_in[3];
    const float* wk  = (const float*)d_in[4];
    const float* wv  = (const float*)d_in[5];
    const float* wb  = (const float*)d_in[6];
    const float* wg  = (const float*)d_in[7];
    const float* bg  = (const float*)d_in[8];
    const float* wo  = (const float*)d_in[9];
    const float* bo  = (const float*)d_in[10];
    float* out = (float*)d_out;

    float* bias = (float*)d_ws;                                  // [h][i][j], 1 MB
    bf16*  q    = (bf16*)((float*)d_ws + (size_t)NH * NPX);
    bf16*  k    = q + (size_t)NPX * CH;
    bf16*  v    = k + (size_t)NPX * CH;
    bf16*  g    = v + (size_t)NPX * CH;
    bf16*  wgt  = g + (size_t)NPX * CH;
    bf16*  wob  = wgt + 4 * 16384;

    prep_kernel<<<80, 256, 0, stream>>>(wq, wk, wv, wg, wo, wgt);
    proj_kernel<<<NPX / BPX, 256, 0, stream>>>(x2d, nw, nb, wgt, bg, wb, q, k, v, g, bias);
    attn_kernel<<<dim3(NRES, NH), 512, 0, stream>>>(q, k, v, bias, g, q);
    out_kernel<<<NPX / BPX, 256, 0, stream>>>(q, wob, bo, out);
}

// Round 17
// 103.573 us; speedup vs baseline: 1.1924x; 1.1924x over previous
//
#include <hip/hip_runtime.h>
#include <hip/hip_bf16.h>

#define NRES 256
#define CH   128
#define NH   4
#define HD   32
#define NPX  (NRES*NRES)   // 65536 pixels
#define BPX  64            // pixels per block in GEMM kernels
#define LOG2E 1.4426950408889634f

typedef __hip_bfloat16 bf16;
typedef __attribute__((ext_vector_type(8))) short bf16x8;
typedef __attribute__((ext_vector_type(4))) float f32x4;
typedef __attribute__((ext_vector_type(16))) float f32x16;
typedef __attribute__((ext_vector_type(2))) unsigned int uint2v;

__device__ __forceinline__ float lo_f(unsigned u) { return __uint_as_float(u << 16); }
__device__ __forceinline__ float hi_f(unsigned u) { return __uint_as_float(u & 0xffff0000u); }
__device__ __forceinline__ float fexp2(float x) { return __builtin_amdgcn_exp2f(x); }
__device__ __forceinline__ unsigned pk2(float a, float b) {
    unsigned short ua = __bfloat16_as_ushort(__float2bfloat16(a));
    unsigned short ub = __bfloat16_as_ushort(__float2bfloat16(b));
    return (unsigned)ua | ((unsigned)ub << 16);
}

// ---------------- Kernel 0: convert weights f32 -> bf16 ----------------
__global__ __launch_bounds__(256) void prep_kernel(const float* __restrict__ wq,
                                                   const float* __restrict__ wk,
                                                   const float* __restrict__ wv,
                                                   const float* __restrict__ wg,
                                                   const float* __restrict__ wo,
                                                   bf16* __restrict__ dst) {
    int mat = blockIdx.x >> 4;
    int off = ((blockIdx.x & 15) * 256 + threadIdx.x) * 4;
    const float* srcs[5] = {wq, wk, wv, wg, wo};
    float4 v4 = *reinterpret_cast<const float4*>(srcs[mat] + off);
    uint2 o;
    o.x = pk2(v4.x, v4.y);
    o.y = pk2(v4.z, v4.w);
    *reinterpret_cast<uint2*>(dst + (size_t)mat * 16384 + off) = o;
}

// ---------------- Kernel 1: LN (in registers) + MFMA projections + pair bias ----------------
__global__ __launch_bounds__(256) void proj_kernel(const float* __restrict__ x2d,
                                                   const float* __restrict__ nw,
                                                   const float* __restrict__ nb,
                                                   const bf16* __restrict__ wgt,
                                                   const float* __restrict__ bg,
                                                   const float* __restrict__ wb,
                                                   bf16* __restrict__ q,
                                                   bf16* __restrict__ k,
                                                   bf16* __restrict__ v,
                                                   bf16* __restrict__ g,
                                                   float* __restrict__ bias) {
    __shared__ short xsb[BPX][128];    // 16 KB swizzled bf16 tile
    int t = threadIdx.x;
    size_t pbase = (size_t)blockIdx.x * BPX;
    int px = t >> 2, lo = t & 3;

    const float* xrow = x2d + (pbase + px) * CH;
    float4 v4[8];
    #pragma unroll
    for (int cc = 0; cc < 8; ++cc)
        v4[cc] = *reinterpret_cast<const float4*>(xrow + 16 * cc + 4 * lo);

    float s = 0.f, ss = 0.f;
    #pragma unroll
    for (int cc = 0; cc < 8; ++cc) {
        s  += v4[cc].x + v4[cc].y + v4[cc].z + v4[cc].w;
        ss += v4[cc].x * v4[cc].x + v4[cc].y * v4[cc].y
            + v4[cc].z * v4[cc].z + v4[cc].w * v4[cc].w;
    }
    s += __shfl_xor(s, 1); ss += __shfl_xor(ss, 1);
    s += __shfl_xor(s, 2); ss += __shfl_xor(ss, 2);
    float mu  = s * (1.0f / CH);
    float var = ss * (1.0f / CH) - mu * mu;
    float rs  = rsqrtf(var + 1e-5f);

    #pragma unroll
    for (int cc = 0; cc < 8; ++cc) {
        int c0 = 16 * cc + 4 * lo;
        float4 wv = *reinterpret_cast<const float4*>(nw + c0);
        float4 bv = *reinterpret_cast<const float4*>(nb + c0);
        v4[cc].x = (v4[cc].x - mu) * rs * wv.x + bv.x;
        v4[cc].y = (v4[cc].y - mu) * rs * wv.y + bv.y;
        v4[cc].z = (v4[cc].z - mu) * rs * wv.z + bv.z;
        v4[cc].w = (v4[cc].w - mu) * rs * wv.w + bv.w;
        int sc = ((((c0 >> 3) ^ px) & 7) << 3) | (c0 & 7) | (c0 & 64);
        uint2 pw;
        pw.x = pk2(v4[cc].x, v4[cc].y);
        pw.y = pk2(v4[cc].z, v4[cc].w);
        *reinterpret_cast<uint2*>(&xsb[px][sc]) = pw;
    }

    // pair bias partials; bias layout [h][i][j] == [h][p], coalesced writes
    float bp0 = 0.f, bp1 = 0.f, bp2 = 0.f, bp3 = 0.f;
    #pragma unroll
    for (int cc = 0; cc < 8; ++cc) {
        int c0 = 16 * cc + 4 * lo;
        float4 w0 = *reinterpret_cast<const float4*>(wb + 0 * CH + c0);
        float4 w1 = *reinterpret_cast<const float4*>(wb + 1 * CH + c0);
        float4 w2 = *reinterpret_cast<const float4*>(wb + 2 * CH + c0);
        float4 w3 = *reinterpret_cast<const float4*>(wb + 3 * CH + c0);
        bp0 += v4[cc].x * w0.x + v4[cc].y * w0.y + v4[cc].z * w0.z + v4[cc].w * w0.w;
        bp1 += v4[cc].x * w1.x + v4[cc].y * w1.y + v4[cc].z * w1.z + v4[cc].w * w1.w;
        bp2 += v4[cc].x * w2.x + v4[cc].y * w2.y + v4[cc].z * w2.z + v4[cc].w * w2.w;
        bp3 += v4[cc].x * w3.x + v4[cc].y * w3.y + v4[cc].z * w3.z + v4[cc].w * w3.w;
    }
    bp0 += __shfl_xor(bp0, 1); bp0 += __shfl_xor(bp0, 2);
    bp1 += __shfl_xor(bp1, 1); bp1 += __shfl_xor(bp1, 2);
    bp2 += __shfl_xor(bp2, 1); bp2 += __shfl_xor(bp2, 2);
    bp3 += __shfl_xor(bp3, 1); bp3 += __shfl_xor(bp3, 2);
    {
        float bv = (lo == 0) ? bp0 : (lo == 1) ? bp1 : (lo == 2) ? bp2 : bp3;
        bias[(size_t)lo * NPX + pbase + px] = bv * LOG2E;
    }
    __syncthreads();

    int w  = t >> 6, l = t & 63;
    int ll = l & 15, lg = l >> 4;
    bf16* Os[4] = {q, k, v, g};
    const float qscale = 0.17677669529663689f * LOG2E;   // 1/sqrt(32) * log2(e)

    #pragma unroll
    for (int mat = 0; mat < 4; ++mat) {
        const bf16* W = wgt + (size_t)mat * 16384;
        bf16x8 bfr[2][4];
        #pragma unroll
        for (int p = 0; p < 2; ++p)
            #pragma unroll
            for (int kt = 0; kt < 4; ++kt)
                bfr[p][kt] = *reinterpret_cast<const bf16x8*>(
                    W + (size_t)((2 * w + p) * 16 + ll) * CH + kt * 32 + lg * 8);

        f32x4 acc[4][2];
        #pragma unroll
        for (int mt = 0; mt < 4; ++mt)
            #pragma unroll
            for (int p = 0; p < 2; ++p) acc[mt][p] = (f32x4){0.f, 0.f, 0.f, 0.f};

        #pragma unroll
        for (int kt = 0; kt < 4; ++kt) {
            bf16x8 a[4];
            #pragma unroll
            for (int mt = 0; mt < 4; ++mt) {
                int row = 16 * mt + ll;
                int gr  = (kt * 4 + lg) ^ (row & 7);
                a[mt] = *reinterpret_cast<const bf16x8*>(&xsb[row][gr * 8]);
            }
            #pragma unroll
            for (int mt = 0; mt < 4; ++mt)
                #pragma unroll
                for (int p = 0; p < 2; ++p)
                    acc[mt][p] = __builtin_amdgcn_mfma_f32_16x16x32_bf16(a[mt], bfr[p][kt], acc[mt][p], 0, 0, 0);
        }

        #pragma unroll
        for (int p = 0; p < 2; ++p) {
            int o = (2 * w + p) * 16 + ll;
            float bgv = (mat == 3) ? bg[o] : 0.f;
            #pragma unroll
            for (int mt = 0; mt < 4; ++mt) {
                #pragma unroll
                for (int r = 0; r < 4; ++r) {
                    int prow = 16 * mt + lg * 4 + r;
                    float valf = acc[mt][p][r];
                    if (mat == 0) valf *= qscale;
                    if (mat == 3) valf = 1.f / (1.f + __expf(-(valf + bgv)));
                    Os[mat][(pbase + prow) * CH + o] = __float2bfloat16(valf);
                }
            }
        }
    }
}

// ---------------- Kernel 2: MFMA flash attention per (m,h) — R11 + K staged in LDS ----------------
__global__ __launch_bounds__(256, 4) void attn_kernel(const bf16* q,
                                                      const bf16* __restrict__ kk,
                                                      const bf16* __restrict__ vv,
                                                      const float* __restrict__ bias,
                                                      const bf16* __restrict__ gg,
                                                      bf16* attn) {
    __shared__ short kl[NRES][HD];     // 16 KB, K rows, granule-swizzled
    __shared__ short vt[HD][NRES];     // 16 KB, transposed V, granule-XOR swizzled

    int t   = threadIdx.x;
    int w   = t >> 6;
    int l   = t & 63;
    int l31 = l & 31;
    int hi5 = l >> 5;
    int m = blockIdx.x, h = blockIdx.y;
    size_t base = ((size_t)m * NRES) * CH + (size_t)h * HD;

    // stage K (granule-swizzled rows) and V (transposed + swizzled)
    for (int it = 0; it < 4; ++it) {
        int e8 = t + 256 * it;          // 0..1023
        int j  = e8 >> 2;
        int g  = e8 & 3;
        int d0 = g * 8;
        uint4 ku = *reinterpret_cast<const uint4*>(kk + base + (size_t)j * CH + d0);
        *reinterpret_cast<uint4*>(&kl[j][(g ^ (j & 3) ^ ((j >> 2) & 3)) * 8]) = ku;
        uint4 vu = *reinterpret_cast<const uint4*>(vv + base + (size_t)j * CH + d0);
        union { uint4 u; short s[8]; } vc; vc.u = vu;
        #pragma unroll
        for (int s = 0; s < 8; ++s)
            vt[d0 + s][j ^ (8 * s)] = vc.s[s];
    }

    // Q fragments (B-operand): col i = w*64+ig*32+l31, k = 16*tt + 8*hi5 + e
    bf16x8 qf[2][2];
    #pragma unroll
    for (int ig = 0; ig < 2; ++ig)
        #pragma unroll
        for (int tt = 0; tt < 2; ++tt)
            qf[ig][tt] = *reinterpret_cast<const bf16x8*>(
                q + base + (size_t)(w * 64 + ig * 32 + l31) * CH + tt * 16 + hi5 * 8);

    __syncthreads();

    float m_run[2] = {-1e30f, -1e30f};
    float l_run[2] = {0.f, 0.f};
    f32x16 oacc[2];
    #pragma unroll
    for (int ig = 0; ig < 2; ++ig)
        #pragma unroll
        for (int r = 0; r < 16; ++r) oacc[ig][r] = 0.f;

    const float* bh = bias + (size_t)h * NPX;

    for (int jt = 0; jt < 8; ++jt) {
        int j0 = jt * 32;
        int jr = j0 + l31;
        int ksw = (jr & 3) ^ ((jr >> 2) & 3);

        // K fragments from LDS (A-operand): row j = jr, k = d
        bf16x8 kf0 = *reinterpret_cast<const bf16x8*>(&kl[jr][(hi5 ^ ksw) * 8]);
        bf16x8 kf1 = *reinterpret_cast<const bf16x8*>(&kl[jr][((2 + hi5) ^ ksw) * 8]);

        // S^T tile: C col i = l31 (+32ig), row j_local = (r&3)+8*(r>>2)+4*hi5
        f32x16 sac[2];
        #pragma unroll
        for (int ig = 0; ig < 2; ++ig) {
            f32x16 zz;
            #pragma unroll
            for (int r = 0; r < 16; ++r) zz[r] = 0.f;
            zz = __builtin_amdgcn_mfma_f32_32x32x16_bf16(kf0, qf[ig][0], zz, 0, 0, 0);
            sac[ig] = __builtin_amdgcn_mfma_f32_32x32x16_bf16(kf1, qf[ig][1], zz, 0, 0, 0);
        }

        __builtin_amdgcn_s_setprio(1);
        // bias add (exp2 domain)
        #pragma unroll
        for (int ig = 0; ig < 2; ++ig) {
            int i = w * 64 + ig * 32 + l31;
            #pragma unroll
            for (int rq = 0; rq < 4; ++rq) {
                float4 b4 = *reinterpret_cast<const float4*>(bh + (size_t)i * NRES + j0 + 8 * rq + 4 * hi5);
                sac[ig][4 * rq + 0] += b4.x; sac[ig][4 * rq + 1] += b4.y;
                sac[ig][4 * rq + 2] += b4.z; sac[ig][4 * rq + 3] += b4.w;
            }
        }
        __builtin_amdgcn_s_setprio(0);

        // online softmax per i-group (exp2 domain), defer-max
        #pragma unroll
        for (int ig = 0; ig < 2; ++ig) {
            float a0 = fmaxf(sac[ig][0], sac[ig][1]),  a1 = fmaxf(sac[ig][2], sac[ig][3]);
            float a2 = fmaxf(sac[ig][4], sac[ig][5]),  a3 = fmaxf(sac[ig][6], sac[ig][7]);
            float a4 = fmaxf(sac[ig][8], sac[ig][9]),  a5 = fmaxf(sac[ig][10], sac[ig][11]);
            float a6 = fmaxf(sac[ig][12], sac[ig][13]), a7 = fmaxf(sac[ig][14], sac[ig][15]);
            float mx = fmaxf(fmaxf(fmaxf(a0, a1), fmaxf(a2, a3)), fmaxf(fmaxf(a4, a5), fmaxf(a6, a7)));
            mx = fmaxf(mx, __shfl_xor(mx, 32));

            if (!__all(mx <= m_run[ig] + 8.f)) {
                float mnew = fmaxf(m_run[ig], mx);
                float sc = fexp2(m_run[ig] - mnew);
                l_run[ig] *= sc;
                #pragma unroll
                for (int r = 0; r < 16; ++r) oacc[ig][r] *= sc;
                m_run[ig] = mnew;
            }
            float mm = m_run[ig];
            #pragma unroll
            for (int r = 0; r < 16; ++r) sac[ig][r] = fexp2(sac[ig][r] - mm);
            float s0 = sac[ig][0] + sac[ig][1],  s1 = sac[ig][2] + sac[ig][3];
            float s2 = sac[ig][4] + sac[ig][5],  s3 = sac[ig][6] + sac[ig][7];
            float s4 = sac[ig][8] + sac[ig][9],  s5 = sac[ig][10] + sac[ig][11];
            float s6 = sac[ig][12] + sac[ig][13], s7 = sac[ig][14] + sac[ig][15];
            float psum = ((s0 + s1) + (s2 + s3)) + ((s4 + s5) + (s6 + s7));
            psum += __shfl_xor(psum, 32);
            l_run[ig] += psum;
        }

        // PV: O^T += V^T * P^T; P B-frag via permlane32_swap
        __builtin_amdgcn_s_setprio(1);
        #pragma unroll
        for (int tt = 0; tt < 2; ++tt) {
            bf16x8 vf = *reinterpret_cast<const bf16x8*>(
                &vt[l31][(j0 + 16 * tt + 8 * hi5) ^ (8 * (l31 & 7))]);
            #pragma unroll
            for (int ig = 0; ig < 2; ++ig) {
                unsigned x0 = pk2(sac[ig][8 * tt + 0], sac[ig][8 * tt + 1]);
                unsigned x1 = pk2(sac[ig][8 * tt + 2], sac[ig][8 * tt + 3]);
                unsigned y0 = pk2(sac[ig][8 * tt + 4], sac[ig][8 * tt + 5]);
                unsigned y1 = pk2(sac[ig][8 * tt + 6], sac[ig][8 * tt + 7]);
                uint2v r0 = __builtin_amdgcn_permlane32_swap(x0, y0, false, false);
                uint2v r1 = __builtin_amdgcn_permlane32_swap(x1, y1, false, false);
                union { unsigned u[4]; bf16x8 v; } pf;
                pf.u[0] = r0[0];  // k 0,1
                pf.u[1] = r1[0];  // k 2,3
                pf.u[2] = r0[1];  // k 4,5
                pf.u[3] = r1[1];  // k 6,7
                oacc[ig] = __builtin_amdgcn_mfma_f32_32x32x16_bf16(vf, pf.v, oacc[ig], 0, 0, 0);
            }
        }
        __builtin_amdgcn_s_setprio(0);
    }

    // epilogue: normalize, gate, store
    #pragma unroll
    for (int ig = 0; ig < 2; ++ig) {
        float inv = 1.f / l_run[ig];
        size_t prow = base + (size_t)(w * 64 + ig * 32 + l31) * CH;
        #pragma unroll
        for (int rq = 0; rq < 4; ++rq) {
            int d0 = 8 * rq + 4 * hi5;
            uint2 gu = *reinterpret_cast<const uint2*>(gg + prow + d0);
            float g0 = lo_f(gu.x), g1 = hi_f(gu.x), g2 = lo_f(gu.y), g3 = hi_f(gu.y);
            uint2 ow;
            ow.x = pk2(oacc[ig][4 * rq + 0] * inv * g0, oacc[ig][4 * rq + 1] * inv * g1);
            ow.y = pk2(oacc[ig][4 * rq + 2] * inv * g2, oacc[ig][4 * rq + 3] * inv * g3);
            *reinterpret_cast<uint2*>(attn + prow + d0) = ow;
        }
    }
}

// ---------------- Kernel 3: MFMA output projection (f32 out) ----------------
__global__ __launch_bounds__(256) void out_kernel(const bf16* __restrict__ ga,
                                                  const bf16* __restrict__ wob,
                                                  const float* __restrict__ bo,
                                                  float* __restrict__ out) {
    __shared__ short xsb[BPX][128];
    int t = threadIdx.x;
    size_t pbase = (size_t)blockIdx.x * BPX;

    for (int it = 0; it < 4; ++it) {
        int idx = (it * 256 + t) * 8;
        int px = idx >> 7, c = idx & 127;
        int gr = c >> 3;
        uint4 u = *reinterpret_cast<const uint4*>(ga + pbase * CH + idx);
        *reinterpret_cast<uint4*>(&xsb[px][(gr ^ (px & 7)) * 8]) = u;
    }
    __syncthreads();

    int w  = t >> 6, l = t & 63;
    int ll = l & 15, lg = l >> 4;

    bf16x8 bfr[2][4];
    #pragma unroll
    for (int p = 0; p < 2; ++p)
        #pragma unroll
        for (int kt = 0; kt < 4; ++kt)
            bfr[p][kt] = *reinterpret_cast<const bf16x8*>(
                wob + (size_t)((2 * w + p) * 16 + ll) * CH + kt * 32 + lg * 8);

    f32x4 acc[4][2];
    #pragma unroll
    for (int mt = 0; mt < 4; ++mt)
        #pragma unroll
        for (int p = 0; p < 2; ++p) acc[mt][p] = (f32x4){0.f, 0.f, 0.f, 0.f};

    #pragma unroll
    for (int kt = 0; kt < 4; ++kt) {
        bf16x8 a[4];
        #pragma unroll
        for (int mt = 0; mt < 4; ++mt) {
            int row = 16 * mt + ll;
            int gr  = (kt * 4 + lg) ^ (row & 7);
            a[mt] = *reinterpret_cast<const bf16x8*>(&xsb[row][gr * 8]);
        }
        #pragma unroll
        for (int mt = 0; mt < 4; ++mt)
            #pragma unroll
            for (int p = 0; p < 2; ++p)
                acc[mt][p] = __builtin_amdgcn_mfma_f32_16x16x32_bf16(a[mt], bfr[p][kt], acc[mt][p], 0, 0, 0);
    }

    #pragma unroll
    for (int p = 0; p < 2; ++p) {
        int o = (2 * w + p) * 16 + ll;
        float bov = bo[o];
        #pragma unroll
        for (int mt = 0; mt < 4; ++mt)
            #pragma unroll
            for (int r = 0; r < 4; ++r) {
                int prow = 16 * mt + lg * 4 + r;
                out[(pbase + prow) * CH + o] = acc[mt][p][r] + bov;
            }
    }
}

extern "C" void kernel_launch(void* const* d_in, const int* in_sizes, int n_in,
                              void* d_out, int out_size, void* d_ws, size_t ws_size,
                              hipStream_t stream) {
    const float* x2d = (const float*)d_in[0];
    const float* nw  = (const float*)d_in[1];
    const float* nb  = (const float*)d_in[2];
    const float* wq  = (const float*)d_in[3];
    const float* wk  = (const float*)d_in[4];
    const float* wv  = (const float*)d_in[5];
    const float* wb  = (const float*)d_in[6];
    const float* wg  = (const float*)d_in[7];
    const float* bg  = (const float*)d_in[8];
    const float* wo  = (const float*)d_in[9];
    const float* bo  = (const float*)d_in[10];
    float* out = (float*)d_out;

    float* bias = (float*)d_ws;                                  // [h][i][j], 1 MB
    bf16*  q    = (bf16*)((float*)d_ws + (size_t)NH * NPX);
    bf16*  k    = q + (size_t)NPX * CH;
    bf16*  v    = k + (size_t)NPX * CH;
    bf16*  g    = v + (size_t)NPX * CH;
    bf16*  wgt  = g + (size_t)NPX * CH;
    bf16*  wob  = wgt + 4 * 16384;

    prep_kernel<<<80, 256, 0, stream>>>(wq, wk, wv, wg, wo, wgt);
    proj_kernel<<<NPX / BPX, 256, 0, stream>>>(x2d, nw, nb, wgt, bg, wb, q, k, v, g, bias);
    attn_kernel<<<dim3(NRES, NH), 256, 0, stream>>>(q, k, v, bias, g, q);
    out_kernel<<<NPX / BPX, 256, 0, stream>>>(q, wob, bo, out);
}

// Round 18
// 92.327 us; speedup vs baseline: 1.3376x; 1.1218x over previous
//
#include <hip/hip_runtime.h>
#include <hip/hip_bf16.h>

#define NRES 256
#define CH   128
#define NH   4
#define HD   32
#define NPX  (NRES*NRES)   // 65536 pixels
#define BPX  64            // pixels per block in GEMM kernels
#define LOG2E 1.4426950408889634f

typedef __hip_bfloat16 bf16;
typedef __attribute__((ext_vector_type(8))) short bf16x8;
typedef __attribute__((ext_vector_type(4))) float f32x4;
typedef __attribute__((ext_vector_type(16))) float f32x16;
typedef __attribute__((ext_vector_type(2))) unsigned int uint2v;

__device__ __forceinline__ float lo_f(unsigned u) { return __uint_as_float(u << 16); }
__device__ __forceinline__ float hi_f(unsigned u) { return __uint_as_float(u & 0xffff0000u); }
__device__ __forceinline__ float fexp2(float x) { return __builtin_amdgcn_exp2f(x); }
__device__ __forceinline__ unsigned pk2(float a, float b) {
    unsigned short ua = __bfloat16_as_ushort(__float2bfloat16(a));
    unsigned short ub = __bfloat16_as_ushort(__float2bfloat16(b));
    return (unsigned)ua | ((unsigned)ub << 16);
}

// ---------------- Kernel 0: convert weights f32 -> bf16 ----------------
__global__ __launch_bounds__(256) void prep_kernel(const float* __restrict__ wq,
                                                   const float* __restrict__ wk,
                                                   const float* __restrict__ wv,
                                                   const float* __restrict__ wg,
                                                   const float* __restrict__ wo,
                                                   bf16* __restrict__ dst) {
    int mat = blockIdx.x >> 4;
    int off = ((blockIdx.x & 15) * 256 + threadIdx.x) * 4;
    const float* srcs[5] = {wq, wk, wv, wg, wo};
    float4 v4 = *reinterpret_cast<const float4*>(srcs[mat] + off);
    uint2 o;
    o.x = pk2(v4.x, v4.y);
    o.y = pk2(v4.z, v4.w);
    *reinterpret_cast<uint2*>(dst + (size_t)mat * 16384 + off) = o;
}

// ---------------- Kernel 1: LN (in registers) + MFMA projections + pair bias ----------------
__global__ __launch_bounds__(256) void proj_kernel(const float* __restrict__ x2d,
                                                   const float* __restrict__ nw,
                                                   const float* __restrict__ nb,
                                                   const bf16* __restrict__ wgt,
                                                   const float* __restrict__ bg,
                                                   const float* __restrict__ wb,
                                                   bf16* __restrict__ q,
                                                   bf16* __restrict__ k,
                                                   bf16* __restrict__ v,
                                                   bf16* __restrict__ g,
                                                   float* __restrict__ bias) {
    __shared__ short xsb[BPX][128];    // 16 KB swizzled bf16 tile
    int t = threadIdx.x;
    size_t pbase = (size_t)blockIdx.x * BPX;
    int px = t >> 2, lo = t & 3;

    const float* xrow = x2d + (pbase + px) * CH;
    float4 v4[8];
    #pragma unroll
    for (int cc = 0; cc < 8; ++cc)
        v4[cc] = *reinterpret_cast<const float4*>(xrow + 16 * cc + 4 * lo);

    float s = 0.f, ss = 0.f;
    #pragma unroll
    for (int cc = 0; cc < 8; ++cc) {
        s  += v4[cc].x + v4[cc].y + v4[cc].z + v4[cc].w;
        ss += v4[cc].x * v4[cc].x + v4[cc].y * v4[cc].y
            + v4[cc].z * v4[cc].z + v4[cc].w * v4[cc].w;
    }
    s += __shfl_xor(s, 1); ss += __shfl_xor(ss, 1);
    s += __shfl_xor(s, 2); ss += __shfl_xor(ss, 2);
    float mu  = s * (1.0f / CH);
    float var = ss * (1.0f / CH) - mu * mu;
    float rs  = rsqrtf(var + 1e-5f);

    #pragma unroll
    for (int cc = 0; cc < 8; ++cc) {
        int c0 = 16 * cc + 4 * lo;
        float4 wv = *reinterpret_cast<const float4*>(nw + c0);
        float4 bv = *reinterpret_cast<const float4*>(nb + c0);
        v4[cc].x = (v4[cc].x - mu) * rs * wv.x + bv.x;
        v4[cc].y = (v4[cc].y - mu) * rs * wv.y + bv.y;
        v4[cc].z = (v4[cc].z - mu) * rs * wv.z + bv.z;
        v4[cc].w = (v4[cc].w - mu) * rs * wv.w + bv.w;
        int sc = ((((c0 >> 3) ^ px) & 7) << 3) | (c0 & 7) | (c0 & 64);
        uint2 pw;
        pw.x = pk2(v4[cc].x, v4[cc].y);
        pw.y = pk2(v4[cc].z, v4[cc].w);
        *reinterpret_cast<uint2*>(&xsb[px][sc]) = pw;
    }

    // pair bias partials; bias layout [h][i][j] == [h][p], coalesced writes
    float bp0 = 0.f, bp1 = 0.f, bp2 = 0.f, bp3 = 0.f;
    #pragma unroll
    for (int cc = 0; cc < 8; ++cc) {
        int c0 = 16 * cc + 4 * lo;
        float4 w0 = *reinterpret_cast<const float4*>(wb + 0 * CH + c0);
        float4 w1 = *reinterpret_cast<const float4*>(wb + 1 * CH + c0);
        float4 w2 = *reinterpret_cast<const float4*>(wb + 2 * CH + c0);
        float4 w3 = *reinterpret_cast<const float4*>(wb + 3 * CH + c0);
        bp0 += v4[cc].x * w0.x + v4[cc].y * w0.y + v4[cc].z * w0.z + v4[cc].w * w0.w;
        bp1 += v4[cc].x * w1.x + v4[cc].y * w1.y + v4[cc].z * w1.z + v4[cc].w * w1.w;
        bp2 += v4[cc].x * w2.x + v4[cc].y * w2.y + v4[cc].z * w2.z + v4[cc].w * w2.w;
        bp3 += v4[cc].x * w3.x + v4[cc].y * w3.y + v4[cc].z * w3.z + v4[cc].w * w3.w;
    }
    bp0 += __shfl_xor(bp0, 1); bp0 += __shfl_xor(bp0, 2);
    bp1 += __shfl_xor(bp1, 1); bp1 += __shfl_xor(bp1, 2);
    bp2 += __shfl_xor(bp2, 1); bp2 += __shfl_xor(bp2, 2);
    bp3 += __shfl_xor(bp3, 1); bp3 += __shfl_xor(bp3, 2);
    {
        float bv = (lo == 0) ? bp0 : (lo == 1) ? bp1 : (lo == 2) ? bp2 : bp3;
        bias[(size_t)lo * NPX + pbase + px] = bv * LOG2E;
    }
    __syncthreads();

    int w  = t >> 6, l = t & 63;
    int ll = l & 15, lg = l >> 4;
    bf16* Os[4] = {q, k, v, g};
    const float qscale = 0.17677669529663689f * LOG2E;   // 1/sqrt(32) * log2(e)

    #pragma unroll
    for (int mat = 0; mat < 4; ++mat) {
        const bf16* W = wgt + (size_t)mat * 16384;
        bf16x8 bfr[2][4];
        #pragma unroll
        for (int p = 0; p < 2; ++p)
            #pragma unroll
            for (int kt = 0; kt < 4; ++kt)
                bfr[p][kt] = *reinterpret_cast<const bf16x8*>(
                    W + (size_t)((2 * w + p) * 16 + ll) * CH + kt * 32 + lg * 8);

        f32x4 acc[4][2];
        #pragma unroll
        for (int mt = 0; mt < 4; ++mt)
            #pragma unroll
            for (int p = 0; p < 2; ++p) acc[mt][p] = (f32x4){0.f, 0.f, 0.f, 0.f};

        #pragma unroll
        for (int kt = 0; kt < 4; ++kt) {
            bf16x8 a[4];
            #pragma unroll
            for (int mt = 0; mt < 4; ++mt) {
                int row = 16 * mt + ll;
                int gr  = (kt * 4 + lg) ^ (row & 7);
                a[mt] = *reinterpret_cast<const bf16x8*>(&xsb[row][gr * 8]);
            }
            #pragma unroll
            for (int mt = 0; mt < 4; ++mt)
                #pragma unroll
                for (int p = 0; p < 2; ++p)
                    acc[mt][p] = __builtin_amdgcn_mfma_f32_16x16x32_bf16(a[mt], bfr[p][kt], acc[mt][p], 0, 0, 0);
        }

        #pragma unroll
        for (int p = 0; p < 2; ++p) {
            int o = (2 * w + p) * 16 + ll;
            float bgv = (mat == 3) ? bg[o] : 0.f;
            #pragma unroll
            for (int mt = 0; mt < 4; ++mt) {
                #pragma unroll
                for (int r = 0; r < 4; ++r) {
                    int prow = 16 * mt + lg * 4 + r;
                    float valf = acc[mt][p][r];
                    if (mat == 0) valf *= qscale;
                    if (mat == 3) valf = 1.f / (1.f + __expf(-(valf + bgv)));
                    Os[mat][(pbase + prow) * CH + o] = __float2bfloat16(valf);
                }
            }
        }
    }
}

// ---------------- Kernel 1b: reshape bias [h][i][j] -> biasI [h][i>>5][j][i&31] ----------------
// grid 128: h(4) x ig32(8) x jt4(4); LDS transpose, coalesced both sides
__global__ __launch_bounds__(256) void ibias_kernel(const float* __restrict__ bias,
                                                    float* __restrict__ biasI) {
    __shared__ float tile[32][65];
    int h   = blockIdx.x >> 5;
    int g32 = (blockIdx.x >> 2) & 7;
    int jt4 = blockIdx.x & 3;
    int t   = threadIdx.x;

    const float* src = bias + (size_t)h * NPX + (size_t)(g32 * 32) * NRES + jt4 * 64;
    int jr = t & 63, ir = t >> 6;
    #pragma unroll
    for (int it = 0; it < 8; ++it) {
        int i = ir + 4 * it;
        tile[i][jr] = src[(size_t)i * NRES + jr];
    }
    __syncthreads();

    float* dst = biasI + ((size_t)(h * 8 + g32) * NRES + jt4 * 64) * 32;
    int i5 = t & 31, jw = t >> 5;
    #pragma unroll
    for (int it = 0; it < 8; ++it) {
        int j = jw + 8 * it;
        dst[(size_t)j * 32 + i5] = tile[i5][j];
    }
}

// ---------------- Kernel 2: MFMA flash attention per (m,h) — coalesced biasI reads ----------------
__global__ __launch_bounds__(256, 3) void attn_kernel(const bf16* q,
                                                      const bf16* __restrict__ kk,
                                                      const bf16* __restrict__ vv,
                                                      const float* __restrict__ biasI,
                                                      const bf16* __restrict__ gg,
                                                      bf16* attn) {
    __shared__ short kl[NRES][HD];     // 16 KB, K rows, granule-swizzled
    __shared__ short vt[HD][NRES];     // 16 KB, transposed V, granule-XOR swizzled

    int t   = threadIdx.x;
    int w   = t >> 6;
    int l   = t & 63;
    int l31 = l & 31;
    int hi5 = l >> 5;
    int m = blockIdx.x, h = blockIdx.y;
    size_t base = ((size_t)m * NRES) * CH + (size_t)h * HD;

    // stage K (granule-swizzled rows) and V (transposed + swizzled)
    for (int it = 0; it < 4; ++it) {
        int e8 = t + 256 * it;          // 0..1023
        int j  = e8 >> 2;
        int g  = e8 & 3;
        int d0 = g * 8;
        uint4 ku = *reinterpret_cast<const uint4*>(kk + base + (size_t)j * CH + d0);
        *reinterpret_cast<uint4*>(&kl[j][(g ^ (j & 3) ^ ((j >> 2) & 3)) * 8]) = ku;
        uint4 vu = *reinterpret_cast<const uint4*>(vv + base + (size_t)j * CH + d0);
        union { uint4 u; short s[8]; } vc; vc.u = vu;
        #pragma unroll
        for (int s = 0; s < 8; ++s)
            vt[d0 + s][j ^ (8 * s)] = vc.s[s];
    }

    // Q fragments (B-operand): col i = w*64+ig*32+l31, k = 16*tt + 8*hi5 + e
    bf16x8 qf[2][2];
    #pragma unroll
    for (int ig = 0; ig < 2; ++ig)
        #pragma unroll
        for (int tt = 0; tt < 2; ++tt)
            qf[ig][tt] = *reinterpret_cast<const bf16x8*>(
                q + base + (size_t)(w * 64 + ig * 32 + l31) * CH + tt * 16 + hi5 * 8);

    __syncthreads();

    float m_run[2] = {-1e30f, -1e30f};
    float l_run[2] = {0.f, 0.f};
    f32x16 oacc[2];
    #pragma unroll
    for (int ig = 0; ig < 2; ++ig)
        #pragma unroll
        for (int r = 0; r < 16; ++r) oacc[ig][r] = 0.f;

    // biasI base for this (h, wave): i-group index = 2w+ig
    const float* bI0 = biasI + ((size_t)(h * 8 + 2 * w) * NRES) * 32 + l31;

    for (int jt = 0; jt < 8; ++jt) {
        int j0 = jt * 32;
        int jr = j0 + l31;
        int ksw = (jr & 3) ^ ((jr >> 2) & 3);

        // K fragments from LDS (A-operand): row j = jr, k = d
        bf16x8 kf0 = *reinterpret_cast<const bf16x8*>(&kl[jr][(hi5 ^ ksw) * 8]);
        bf16x8 kf1 = *reinterpret_cast<const bf16x8*>(&kl[jr][((2 + hi5) ^ ksw) * 8]);

        // S^T tile: C col i = l31 (+32ig), row j_local = (r&3)+8*(r>>2)+4*hi5
        f32x16 sac[2];
        #pragma unroll
        for (int ig = 0; ig < 2; ++ig) {
            f32x16 zz;
            #pragma unroll
            for (int r = 0; r < 16; ++r) zz[r] = 0.f;
            zz = __builtin_amdgcn_mfma_f32_32x32x16_bf16(kf0, qf[ig][0], zz, 0, 0, 0);
            sac[ig] = __builtin_amdgcn_mfma_f32_32x32x16_bf16(kf1, qf[ig][1], zz, 0, 0, 0);
        }

        // bias add: coalesced scalar dword loads from biasI (lane = i contiguous)
        #pragma unroll
        for (int ig = 0; ig < 2; ++ig) {
            const float* bp = bI0 + (size_t)ig * (NRES * 32) + (size_t)j0 * 32;
            #pragma unroll
            for (int r = 0; r < 16; ++r) {
                int jl = (r & 3) + 8 * (r >> 2) + 4 * hi5;
                sac[ig][r] += bp[(size_t)jl * 32];
            }
        }

        // online softmax per i-group (exp2 domain), defer-max
        #pragma unroll
        for (int ig = 0; ig < 2; ++ig) {
            float a0 = fmaxf(sac[ig][0], sac[ig][1]),  a1 = fmaxf(sac[ig][2], sac[ig][3]);
            float a2 = fmaxf(sac[ig][4], sac[ig][5]),  a3 = fmaxf(sac[ig][6], sac[ig][7]);
            float a4 = fmaxf(sac[ig][8], sac[ig][9]),  a5 = fmaxf(sac[ig][10], sac[ig][11]);
            float a6 = fmaxf(sac[ig][12], sac[ig][13]), a7 = fmaxf(sac[ig][14], sac[ig][15]);
            float mx = fmaxf(fmaxf(fmaxf(a0, a1), fmaxf(a2, a3)), fmaxf(fmaxf(a4, a5), fmaxf(a6, a7)));
            mx = fmaxf(mx, __shfl_xor(mx, 32));

            if (!__all(mx <= m_run[ig] + 8.f)) {
                float mnew = fmaxf(m_run[ig], mx);
                float sc = fexp2(m_run[ig] - mnew);
                l_run[ig] *= sc;
                #pragma unroll
                for (int r = 0; r < 16; ++r) oacc[ig][r] *= sc;
                m_run[ig] = mnew;
            }
            float mm = m_run[ig];
            #pragma unroll
            for (int r = 0; r < 16; ++r) sac[ig][r] = fexp2(sac[ig][r] - mm);
            float s0 = sac[ig][0] + sac[ig][1],  s1 = sac[ig][2] + sac[ig][3];
            float s2 = sac[ig][4] + sac[ig][5],  s3 = sac[ig][6] + sac[ig][7];
            float s4 = sac[ig][8] + sac[ig][9],  s5 = sac[ig][10] + sac[ig][11];
            float s6 = sac[ig][12] + sac[ig][13], s7 = sac[ig][14] + sac[ig][15];
            float psum = ((s0 + s1) + (s2 + s3)) + ((s4 + s5) + (s6 + s7));
            psum += __shfl_xor(psum, 32);
            l_run[ig] += psum;
        }

        // PV: O^T += V^T * P^T; P B-frag via permlane32_swap
        __builtin_amdgcn_s_setprio(1);
        #pragma unroll
        for (int tt = 0; tt < 2; ++tt) {
            bf16x8 vf = *reinterpret_cast<const bf16x8*>(
                &vt[l31][(j0 + 16 * tt + 8 * hi5) ^ (8 * (l31 & 7))]);
            #pragma unroll
            for (int ig = 0; ig < 2; ++ig) {
                unsigned x0 = pk2(sac[ig][8 * tt + 0], sac[ig][8 * tt + 1]);
                unsigned x1 = pk2(sac[ig][8 * tt + 2], sac[ig][8 * tt + 3]);
                unsigned y0 = pk2(sac[ig][8 * tt + 4], sac[ig][8 * tt + 5]);
                unsigned y1 = pk2(sac[ig][8 * tt + 6], sac[ig][8 * tt + 7]);
                uint2v r0 = __builtin_amdgcn_permlane32_swap(x0, y0, false, false);
                uint2v r1 = __builtin_amdgcn_permlane32_swap(x1, y1, false, false);
                union { unsigned u[4]; bf16x8 v; } pf;
                pf.u[0] = r0[0];  // k 0,1
                pf.u[1] = r1[0];  // k 2,3
                pf.u[2] = r0[1];  // k 4,5
                pf.u[3] = r1[1];  // k 6,7
                oacc[ig] = __builtin_amdgcn_mfma_f32_32x32x16_bf16(vf, pf.v, oacc[ig], 0, 0, 0);
            }
        }
        __builtin_amdgcn_s_setprio(0);
    }

    // epilogue: normalize, gate, store
    #pragma unroll
    for (int ig = 0; ig < 2; ++ig) {
        float inv = 1.f / l_run[ig];
        size_t prow = base + (size_t)(w * 64 + ig * 32 + l31) * CH;
        #pragma unroll
        for (int rq = 0; rq < 4; ++rq) {
            int d0 = 8 * rq + 4 * hi5;
            uint2 gu = *reinterpret_cast<const uint2*>(gg + prow + d0);
            float g0 = lo_f(gu.x), g1 = hi_f(gu.x), g2 = lo_f(gu.y), g3 = hi_f(gu.y);
            uint2 ow;
            ow.x = pk2(oacc[ig][4 * rq + 0] * inv * g0, oacc[ig][4 * rq + 1] * inv * g1);
            ow.y = pk2(oacc[ig][4 * rq + 2] * inv * g2, oacc[ig][4 * rq + 3] * inv * g3);
            *reinterpret_cast<uint2*>(attn + prow + d0) = ow;
        }
    }
}

// ---------------- Kernel 3: MFMA output projection (f32 out) ----------------
__global__ __launch_bounds__(256) void out_kernel(const bf16* __restrict__ ga,
                                                  const bf16* __restrict__ wob,
                                                  const float* __restrict__ bo,
                                                  float* __restrict__ out) {
    __shared__ short xsb[BPX][128];
    int t = threadIdx.x;
    size_t pbase = (size_t)blockIdx.x * BPX;

    for (int it = 0; it < 4; ++it) {
        int idx = (it * 256 + t) * 8;
        int px = idx >> 7, c = idx & 127;
        int gr = c >> 3;
        uint4 u = *reinterpret_cast<const uint4*>(ga + pbase * CH + idx);
        *reinterpret_cast<uint4*>(&xsb[px][(gr ^ (px & 7)) * 8]) = u;
    }
    __syncthreads();

    int w  = t >> 6, l = t & 63;
    int ll = l & 15, lg = l >> 4;

    bf16x8 bfr[2][4];
    #pragma unroll
    for (int p = 0; p < 2; ++p)
        #pragma unroll
        for (int kt = 0; kt < 4; ++kt)
            bfr[p][kt] = *reinterpret_cast<const bf16x8*>(
                wob + (size_t)((2 * w + p) * 16 + ll) * CH + kt * 32 + lg * 8);

    f32x4 acc[4][2];
    #pragma unroll
    for (int mt = 0; mt < 4; ++mt)
        #pragma unroll
        for (int p = 0; p < 2; ++p) acc[mt][p] = (f32x4){0.f, 0.f, 0.f, 0.f};

    #pragma unroll
    for (int kt = 0; kt < 4; ++kt) {
        bf16x8 a[4];
        #pragma unroll
        for (int mt = 0; mt < 4; ++mt) {
            int row = 16 * mt + ll;
            int gr  = (kt * 4 + lg) ^ (row & 7);
            a[mt] = *reinterpret_cast<const bf16x8*>(&xsb[row][gr * 8]);
        }
        #pragma unroll
        for (int mt = 0; mt < 4; ++mt)
            #pragma unroll
            for (int p = 0; p < 2; ++p)
                acc[mt][p] = __builtin_amdgcn_mfma_f32_16x16x32_bf16(a[mt], bfr[p][kt], acc[mt][p], 0, 0, 0);
    }

    #pragma unroll
    for (int p = 0; p < 2; ++p) {
        int o = (2 * w + p) * 16 + ll;
        float bov = bo[o];
        #pragma unroll
        for (int mt = 0; mt < 4; ++mt)
            #pragma unroll
            for (int r = 0; r < 4; ++r) {
                int prow = 16 * mt + lg * 4 + r;
                out[(pbase + prow) * CH + o] = acc[mt][p][r] + bov;
            }
    }
}

extern "C" void kernel_launch(void* const* d_in, const int* in_sizes, int n_in,
                              void* d_out, int out_size, void* d_ws, size_t ws_size,
                              hipStream_t stream) {
    const float* x2d = (const float*)d_in[0];
    const float* nw  = (const float*)d_in[1];
    const float* nb  = (const float*)d_in[2];
    const float* wq  = (const float*)d_in[3];
    const float* wk  = (const float*)d_in[4];
    const float* wv  = (const float*)d_in[5];
    const float* wb  = (const float*)d_in[6];
    const float* wg  = (const float*)d_in[7];
    const float* bg  = (const float*)d_in[8];
    const float* wo  = (const float*)d_in[9];
    const float* bo  = (const float*)d_in[10];
    float* out = (float*)d_out;

    float* bias = (float*)d_ws;                                  // [h][i][j], 1 MB
    bf16*  q    = (bf16*)((float*)d_ws + (size_t)NH * NPX);
    bf16*  k    = q + (size_t)NPX * CH;
    bf16*  v    = k + (size_t)NPX * CH;
    bf16*  g    = v + (size_t)NPX * CH;
    bf16*  wgt  = g + (size_t)NPX * CH;
    bf16*  wob  = wgt + 4 * 16384;
    float* biasI = (float*)(wob + 16384);                        // [h][i>>5][j][i&31], 1 MB

    prep_kernel<<<80, 256, 0, stream>>>(wq, wk, wv, wg, wo, wgt);
    proj_kernel<<<NPX / BPX, 256, 0, stream>>>(x2d, nw, nb, wgt, bg, wb, q, k, v, g, bias);
    ibias_kernel<<<128, 256, 0, stream>>>(bias, biasI);
    attn_kernel<<<dim3(NRES, NH), 256, 0, stream>>>(q, k, v, biasI, g, q);
    out_kernel<<<NPX / BPX, 256, 0, stream>>>(q, wob, bo, out);
}